// Round 8
// baseline (218.854 us; speedup 1.0000x reference)
//
#include <hip/hip_runtime.h>
#include <cstdint>
#include <cstddef>

#define BATCH 8
#define NODES 2048
#define IN_DIM 64
#define DTOT 128
#define NKEY 1024
#define QGROUPS 128    // 2048/16 row-groups per batch
#define KGROUPS 64     // 1024/16 u-groups per batch
#define SROW2 516      // score LDS row stride for 512-wide half-rows (2-way bank aliasing only)

typedef _Float16 half8v __attribute__((ext_vector_type(8)));
typedef float float4v __attribute__((ext_vector_type(4)));

__device__ __forceinline__ unsigned key_hi_u(float v) {
    unsigned u = __float_as_uint(v);
    return (u & 0x80000000u) ? ~u : (u | 0x80000000u);
}

__device__ __forceinline__ unsigned long long make_key(float v, int idx) {
    return ((unsigned long long)key_hi_u(v) << 32) | (unsigned)(1023 - idx);
}

__device__ __forceinline__ float key_val(unsigned hi) {
    return __uint_as_float((hi & 0x80000000u) ? (hi & 0x7fffffffu) : ~hi);
}

// ---------------- Kernel 1: projection -> split-fp16 planes in MFMA-fragment layout ----------------
// Fragment layout: plane[b][g][h][l][e], flat = ((bG + g)*4 + h)*512 + l*8 + e
__global__ __launch_bounds__(256) void proj_qk(
    const float* __restrict__ x, const float* __restrict__ Wq, const float* __restrict__ bq,
    const float* __restrict__ Wk, const float* __restrict__ bk,
    _Float16* __restrict__ qfh, _Float16* __restrict__ qfl,
    _Float16* __restrict__ kfh, _Float16* __restrict__ kfl)
{
    __shared__ float xs[64 * 68];
    __shared__ float wsh[64 * 68];

    const int t = threadIdx.x;
    const int blk = blockIdx.x;
    const int b = blk / 96;
    const int idx = blk - b * 96;

    const float* W; const float* bias;
    _Float16* oh; _Float16* ol;
    int nbase, cbase; size_t gbase;
    if (idx < 64) {
        int nt = idx >> 1, ct = idx & 1;
        nbase = nt * 64; cbase = ct * 64;
        W = Wq; bias = bq; oh = qfh; ol = qfl;
        gbase = (size_t)b * QGROUPS + (nbase >> 4);
    } else {
        int i2 = idx - 64;
        int nt = i2 >> 1, ct = i2 & 1;
        nbase = nt * 64; cbase = ct * 64;
        W = Wk; bias = bk; oh = kfh; ol = kfl;
        gbase = (size_t)b * KGROUPS + (nbase >> 4);
    }
    const int hbase = cbase >> 5;

    #pragma unroll
    for (int rep = 0; rep < 4; ++rep) {
        int f = rep * 256 + t;
        int r = f >> 4, d4 = f & 15;
        float4 xv = *(const float4*)(x + ((size_t)(b * NODES + nbase + r)) * IN_DIM + d4 * 4);
        *(float4*)(xs + r * 68 + d4 * 4) = xv;
        float4 wv = *(const float4*)(W + (size_t)(cbase + r) * IN_DIM + d4 * 4);
        *(float4*)(wsh + r * 68 + d4 * 4) = wv;
    }
    __syncthreads();

    const int w = t >> 6, l = t & 63;
    const int n_sel = w * 4 + (l >> 4);
    const int ul = l & 15;

    float acc[4][4];
    #pragma unroll
    for (int i = 0; i < 4; ++i)
        #pragma unroll
        for (int j = 0; j < 4; ++j) acc[i][j] = 0.f;

    #pragma unroll
    for (int d4 = 0; d4 < 16; ++d4) {
        float4 xv[4], wv[4];
        #pragma unroll
        for (int i = 0; i < 4; ++i)
            xv[i] = *(const float4*)(xs + (n_sel * 4 + i) * 68 + d4 * 4);
        #pragma unroll
        for (int j = 0; j < 4; ++j)
            wv[j] = *(const float4*)(wsh + (j * 16 + ul) * 68 + d4 * 4);
        #pragma unroll
        for (int i = 0; i < 4; ++i)
            #pragma unroll
            for (int j = 0; j < 4; ++j)
                acc[i][j] += xv[i].x * wv[j].x + xv[i].y * wv[j].y +
                             xv[i].z * wv[j].z + xv[i].w * wv[j].w;
    }
    __syncthreads();   // reuse xs as the 64x64 fp32 result tile

    #pragma unroll
    for (int j = 0; j < 4; ++j) {
        float bv = bias[cbase + j * 16 + ul];
        #pragma unroll
        for (int i = 0; i < 4; ++i)
            xs[(n_sel * 4 + i) * 68 + j * 16 + ul] = acc[i][j] + bv;
    }
    __syncthreads();

    #pragma unroll
    for (int rep = 0; rep < 2; ++rep) {
        int u = rep * 256 + t;
        int g = u >> 7, hh = (u >> 6) & 1, lf = u & 63;
        const float* src = xs + (g * 16 + (lf & 15)) * 68 + hh * 32 + (lf >> 4) * 8;
        float4 f0 = *(const float4*)src;
        float4 f1 = *(const float4*)(src + 4);
        float tmp[8] = {f0.x, f0.y, f0.z, f0.w, f1.x, f1.y, f1.z, f1.w};
        half8v hv, lv;
        #pragma unroll
        for (int e = 0; e < 8; ++e) {
            _Float16 hi = (_Float16)tmp[e];
            hv[e] = hi;
            lv[e] = (_Float16)(tmp[e] - (float)hi);
        }
        size_t dst = ((gbase + g) * 4 + hbase + hh) * (size_t)512 + lf * 8;
        *(half8v*)(oh + dst) = hv;
        *(half8v*)(ol + dst) = lv;
    }
}

// Exact top-32 of a 512-wide half-row held in sc (8 values/lane). Emits 32 keys to keyrow.
__device__ __forceinline__ void select_pass32(
    const float* R, int ubase, int l,
    unsigned long long* candw, unsigned long long* keyrow)
{
    float4 vv0 = *(const float4*)(R + l * 4);
    float4 vv1 = *(const float4*)(R + 256 + l * 4);
    float elems[8] = {vv0.x, vv0.y, vv0.z, vv0.w, vv1.x, vv1.y, vv1.z, vv1.w};

    float m = elems[0];
    #pragma unroll
    for (int s = 1; s < 8; ++s) m = fmaxf(m, elems[s]);

    // T = 32nd-largest lane-max via bitwise ballot search
    unsigned km = key_hi_u(m);
    unsigned accT = 0u;
    #pragma unroll
    for (int bit = 31; bit >= 0; --bit) {
        unsigned trial = accT | (1u << bit);
        if (__popcll(__ballot(km >= trial)) >= 32) accT = trial;
    }
    const float T = key_val(accT);   // >= 32 half-row elements are >= T

    candw[l] = 0ull;
    __builtin_amdgcn_wave_barrier();
    int total = 0;
    #pragma unroll
    for (int s = 0; s < 8; ++s) {
        float v = elems[s];
        bool p = (v >= T);
        unsigned long long msk = __ballot(p);
        if (p) {
            int pos = total + __popcll(msk & ((1ull << l) - 1ull));
            if (pos < 64) candw[pos] = make_key(v, ubase + (s >> 2) * 256 + l * 4 + (s & 3));
        }
        total += (int)__popcll(msk);
    }
    __builtin_amdgcn_wave_barrier();

    if (total <= 64) {
        unsigned long long key = candw[l];
        unsigned hi = (unsigned)(key >> 32), lo = (unsigned)key;
        unsigned X = 0u;
        #pragma unroll
        for (int bit = 31; bit >= 0; --bit) {
            unsigned trial = X | (1u << bit);
            if (__popcll(__ballot(hi >= trial)) >= 32) X = trial;
        }
        int cgt = __popcll(__ballot(hi > X));
        int rem = 32 - cgt;
        unsigned Y = 0u;
        #pragma unroll
        for (int bit = 9; bit >= 0; --bit) {
            unsigned trial = Y | (1u << bit);
            if (__popcll(__ballot(hi == X && lo >= trial)) >= rem) Y = trial;
        }
        bool win = (hi > X) || (hi == X && lo >= Y);   // exactly 32 winners
        unsigned long long wm = __ballot(win);
        if (win) keyrow[__popcll(wm & ((1ull << l) - 1ull))] = key;
    } else {
        // rare fallback: exact 32-round butterfly extraction over 8 slots/lane
        float vals[8];
        #pragma unroll
        for (int s = 0; s < 8; ++s) vals[s] = elems[s];
        float selv = 0.f; int seli = 0;
        #pragma unroll 1
        for (int it = 0; it < 32; ++it) {
            float bv = -3.4e38f; int bi = 0x7fffffff;
            #pragma unroll
            for (int s = 0; s < 8; ++s) {
                int lu = (s >> 2) * 256 + l * 4 + (s & 3);
                if (vals[s] > bv) { bv = vals[s]; bi = lu; }
            }
            #pragma unroll
            for (int off = 1; off < 64; off <<= 1) {
                float ov = __shfl_xor(bv, off, 64);
                int oi = __shfl_xor(bi, off, 64);
                if (ov > bv || (ov == bv && oi < bi)) { bv = ov; bi = oi; }
            }
            if (l == it) { selv = bv; seli = bi; }
            if (((bi >> 2) & 63) == l) {
                int slot = ((bi >> 8) << 2) + (bi & 3);
                #pragma unroll
                for (int s = 0; s < 8; ++s) if (s == slot) vals[s] = -3.4e38f;
            }
        }
        if (l < 32) keyrow[l] = make_key(selv, ubase + seli);
    }
    __builtin_amdgcn_wave_barrier();
}

// ---------------- Kernel 2: fused MFMA scores (2 u-passes) + exact top-32 + row write ----------------
// Block: 16 n-rows x 1024 u, 512 threads. Pass p: wave w scores u-groups p*32 + w*4 + i (i<4),
// then selects half-row top-32 for rows {2w, 2w+1}; final merge of 2x32 keys -> output.
__global__ __launch_bounds__(512, 6) void scores_topk(
    const _Float16* __restrict__ qfh, const _Float16* __restrict__ qfl,
    const _Float16* __restrict__ kfh, const _Float16* __restrict__ kfl,
    const float* __restrict__ mlpw, const float* __restrict__ mlpb,
    float* __restrict__ adj)
{
    __shared__ float sc[16 * SROW2];             // 33.0 KB half-row scores
    __shared__ unsigned long long cand[8][64];   // 4 KB
    __shared__ unsigned long long keys[16][64];  // 8 KB: per row, 32 keys per pass

    const int t = threadIdx.x;
    const int blk = blockIdx.x;
    const int b = blk & 7;                       // batch == XCD affinity (k stays L2-hot)
    const int gq = blk >> 3;                     // q row-group (16 rows)

    const int w = t >> 6, l = t & 63;
    const int quad = l >> 4, lane16 = l & 15;

    // A fragments: coalesced 16B loads from fragment-layout q
    half8v Ah[4], Al[4];
    #pragma unroll
    for (int h = 0; h < 4; ++h) {
        size_t a = (((size_t)b * QGROUPS + gq) * 4 + h) * 512 + l * 8;
        Ah[h] = *(const half8v*)(qfh + a);
        Al[h] = *(const half8v*)(qfl + a);
    }

    float mw[4][4], mb4[4];
    #pragma unroll
    for (int o = 0; o < 4; ++o) {
        mb4[o] = mlpb[o];
        #pragma unroll
        for (int h = 0; h < 4; ++h) mw[o][h] = mlpw[o * 4 + h];
    }
    const float INV = 0.17677669529663687f;      // 1/sqrt(32)

    #pragma unroll 1
    for (int pass = 0; pass < 2; ++pass) {
        #pragma unroll 2
        for (int i = 0; i < 4; ++i) {
            const int g = pass * 32 + w * 4 + i;
            float4v C[4];
            #pragma unroll
            for (int h = 0; h < 4; ++h) {
                size_t a = (((size_t)b * KGROUPS + g) * 4 + h) * 512 + l * 8;
                half8v Bh = *(const half8v*)(kfh + a);
                half8v Bl = *(const half8v*)(kfl + a);
                float4v c = {0.f, 0.f, 0.f, 0.f};
                c = __builtin_amdgcn_mfma_f32_16x16x32_f16(Ah[h], Bh, c, 0, 0, 0);
                c = __builtin_amdgcn_mfma_f32_16x16x32_f16(Ah[h], Bl, c, 0, 0, 0);
                c = __builtin_amdgcn_mfma_f32_16x16x32_f16(Al[h], Bh, c, 0, 0, 0);
                C[h] = c;
            }
            #pragma unroll
            for (int r = 0; r < 4; ++r) {
                float a0 = C[0][r] * INV, a1 = C[1][r] * INV;
                float a2 = C[2][r] * INV, a3 = C[3][r] * INV;
                float ssum = a0 + a1 + a2 + a3;
                #pragma unroll
                for (int o = 0; o < 4; ++o) {
                    float to = mw[o][0] * a0 + mw[o][1] * a1 + mw[o][2] * a2 + mw[o][3] * a3 + mb4[o];
                    ssum += fmaxf(to, 0.f);
                }
                sc[(quad * 4 + r) * SROW2 + (w * 4 + i) * 16 + lane16] = ssum;
            }
        }
        __syncthreads();                          // half-row scores complete

        for (int rr = 0; rr < 2; ++rr) {
            const int row = w * 2 + rr;
            select_pass32(sc + row * SROW2, pass * 512, l, cand[w], &keys[row][pass * 32]);
        }
        if (pass == 0) __syncthreads();           // sc reads done before pass-1 overwrites
    }

    // ---- merge: exact top-32 of the 64 saved keys; rebuild + write (wave-local rows) ----
    for (int rr = 0; rr < 2; ++rr) {
        const int row = w * 2 + rr;
        unsigned long long key = keys[row][l];
        unsigned hi = (unsigned)(key >> 32), lo = (unsigned)key;

        unsigned X = 0u;
        #pragma unroll
        for (int bit = 31; bit >= 0; --bit) {
            unsigned trial = X | (1u << bit);
            if (__popcll(__ballot(hi >= trial)) >= 32) X = trial;
        }
        int cgt = __popcll(__ballot(hi > X));
        int rem = 32 - cgt;
        unsigned Y = 0u;
        #pragma unroll
        for (int bit = 9; bit >= 0; --bit) {
            unsigned trial = Y | (1u << bit);
            if (__popcll(__ballot(hi == X && lo >= trial)) >= rem) Y = trial;
        }
        const bool win = (hi > X) || (hi == X && lo >= Y);   // exactly 32 winners
        const float wval = key_val(hi);
        const int widx = 1023 - (int)lo;

        float* R = sc + row * SROW2;
        float* rowptr = adj + ((size_t)(b * NODES + gq * 16 + row)) * NODES;
        const float4 z4 = make_float4(0.f, 0.f, 0.f, 0.f);

        // half 0: cols [0, 512)
        __builtin_amdgcn_wave_barrier();
        *(float4*)(R + l * 4) = z4;
        *(float4*)(R + 256 + l * 4) = z4;
        __builtin_amdgcn_wave_barrier();
        if (win && widx < 512) R[widx] = wval;
        __builtin_amdgcn_wave_barrier();
        #pragma unroll
        for (int jj = 0; jj < 2; ++jj)
            *(float4*)(rowptr + jj * 256 + l * 4) = *(const float4*)(R + jj * 256 + l * 4);

        // half 1: cols [512, 1024)
        __builtin_amdgcn_wave_barrier();
        *(float4*)(R + l * 4) = z4;
        *(float4*)(R + 256 + l * 4) = z4;
        __builtin_amdgcn_wave_barrier();
        if (win && widx >= 512) R[widx - 512] = wval;
        __builtin_amdgcn_wave_barrier();
        #pragma unroll
        for (int jj = 0; jj < 2; ++jj)
            *(float4*)(rowptr + 512 + jj * 256 + l * 4) = *(const float4*)(R + jj * 256 + l * 4);

        // cols [1024, 2048) are always zero
        #pragma unroll
        for (int jj = 0; jj < 4; ++jj)
            *(float4*)(rowptr + 1024 + jj * 256 + l * 4) = z4;
    }
}

extern "C" void kernel_launch(void* const* d_in, const int* in_sizes, int n_in,
                              void* d_out, int out_size, void* d_ws, size_t ws_size,
                              hipStream_t stream) {
    const float* x    = (const float*)d_in[0];
    const float* Wq   = (const float*)d_in[1];
    const float* bq   = (const float*)d_in[2];
    const float* Wk   = (const float*)d_in[3];
    const float* bk   = (const float*)d_in[4];
    const float* mlpw = (const float*)d_in[5];
    const float* mlpb = (const float*)d_in[6];
    // ln_g, ln_b feed only the deleted adj_static -> unused.

    _Float16* qfh = (_Float16*)d_ws;                        // 4 MB
    _Float16* qfl = qfh + (size_t)BATCH * NODES * DTOT;     // 4 MB
    _Float16* kfh = qfl + (size_t)BATCH * NODES * DTOT;     // 2 MB
    _Float16* kfl = kfh + (size_t)BATCH * NKEY * DTOT;      // 2 MB (total 12 MB)
    float* adj = (float*)d_out;

    proj_qk<<<dim3(BATCH * 96), dim3(256), 0, stream>>>(x, Wq, bq, Wk, bk, qfh, qfl, kfh, kfl);
    scores_topk<<<dim3(BATCH * QGROUPS), dim3(512), 0, stream>>>(qfh, qfl, kfh, kfl, mlpw, mlpb, adj);
}

// Round 9
// 215.694 us; speedup vs baseline: 1.0147x; 1.0147x over previous
//
#include <hip/hip_runtime.h>
#include <cstdint>
#include <cstddef>

#define BATCH 8
#define NODES 2048
#define IN_DIM 64
#define DTOT 128
#define NKEY 1024
#define QGROUPS 128    // 2048/16 row-groups per batch
#define KGROUPS 64     // 1024/16 u-groups per batch
#define SROW2 516      // score LDS row stride for 512-wide half-rows (2-way bank aliasing only)

typedef _Float16 half8v __attribute__((ext_vector_type(8)));
typedef float float4v __attribute__((ext_vector_type(4)));

__device__ __forceinline__ unsigned key_hi_u(float v) {
    unsigned u = __float_as_uint(v);
    return (u & 0x80000000u) ? ~u : (u | 0x80000000u);
}

__device__ __forceinline__ unsigned long long make_key(float v, int idx) {
    return ((unsigned long long)key_hi_u(v) << 32) | (unsigned)(1023 - idx);
}

__device__ __forceinline__ float key_val(unsigned hi) {
    return __uint_as_float((hi & 0x80000000u) ? (hi & 0x7fffffffu) : ~hi);
}

__device__ __forceinline__ float uload(const float* p) {   // wave-uniform load -> SGPR
    return __int_as_float(__builtin_amdgcn_readfirstlane(__float_as_int(*p)));
}

// ---------------- Kernel 1: projection -> split-fp16 planes in MFMA-fragment layout ----------------
// Fragment layout: plane[b][g][h][l][e], flat = ((bG + g)*4 + h)*512 + l*8 + e
__global__ __launch_bounds__(256) void proj_qk(
    const float* __restrict__ x, const float* __restrict__ Wq, const float* __restrict__ bq,
    const float* __restrict__ Wk, const float* __restrict__ bk,
    _Float16* __restrict__ qfh, _Float16* __restrict__ qfl,
    _Float16* __restrict__ kfh, _Float16* __restrict__ kfl)
{
    __shared__ float xs[64 * 68];
    __shared__ float wsh[64 * 68];

    const int t = threadIdx.x;
    const int blk = blockIdx.x;
    const int b = blk / 96;
    const int idx = blk - b * 96;

    const float* W; const float* bias;
    _Float16* oh; _Float16* ol;
    int nbase, cbase; size_t gbase;
    if (idx < 64) {
        int nt = idx >> 1, ct = idx & 1;
        nbase = nt * 64; cbase = ct * 64;
        W = Wq; bias = bq; oh = qfh; ol = qfl;
        gbase = (size_t)b * QGROUPS + (nbase >> 4);
    } else {
        int i2 = idx - 64;
        int nt = i2 >> 1, ct = i2 & 1;
        nbase = nt * 64; cbase = ct * 64;
        W = Wk; bias = bk; oh = kfh; ol = kfl;
        gbase = (size_t)b * KGROUPS + (nbase >> 4);
    }
    const int hbase = cbase >> 5;

    #pragma unroll
    for (int rep = 0; rep < 4; ++rep) {
        int f = rep * 256 + t;
        int r = f >> 4, d4 = f & 15;
        float4 xv = *(const float4*)(x + ((size_t)(b * NODES + nbase + r)) * IN_DIM + d4 * 4);
        *(float4*)(xs + r * 68 + d4 * 4) = xv;
        float4 wv = *(const float4*)(W + (size_t)(cbase + r) * IN_DIM + d4 * 4);
        *(float4*)(wsh + r * 68 + d4 * 4) = wv;
    }
    __syncthreads();

    const int w = t >> 6, l = t & 63;
    const int n_sel = w * 4 + (l >> 4);
    const int ul = l & 15;

    float acc[4][4];
    #pragma unroll
    for (int i = 0; i < 4; ++i)
        #pragma unroll
        for (int j = 0; j < 4; ++j) acc[i][j] = 0.f;

    #pragma unroll
    for (int d4 = 0; d4 < 16; ++d4) {
        float4 xv[4], wv[4];
        #pragma unroll
        for (int i = 0; i < 4; ++i)
            xv[i] = *(const float4*)(xs + (n_sel * 4 + i) * 68 + d4 * 4);
        #pragma unroll
        for (int j = 0; j < 4; ++j)
            wv[j] = *(const float4*)(wsh + (j * 16 + ul) * 68 + d4 * 4);
        #pragma unroll
        for (int i = 0; i < 4; ++i)
            #pragma unroll
            for (int j = 0; j < 4; ++j)
                acc[i][j] += xv[i].x * wv[j].x + xv[i].y * wv[j].y +
                             xv[i].z * wv[j].z + xv[i].w * wv[j].w;
    }
    __syncthreads();   // reuse xs as the 64x64 fp32 result tile

    #pragma unroll
    for (int j = 0; j < 4; ++j) {
        float bv = bias[cbase + j * 16 + ul];
        #pragma unroll
        for (int i = 0; i < 4; ++i)
            xs[(n_sel * 4 + i) * 68 + j * 16 + ul] = acc[i][j] + bv;
    }
    __syncthreads();

    #pragma unroll
    for (int rep = 0; rep < 2; ++rep) {
        int u = rep * 256 + t;
        int g = u >> 7, hh = (u >> 6) & 1, lf = u & 63;
        const float* src = xs + (g * 16 + (lf & 15)) * 68 + hh * 32 + (lf >> 4) * 8;
        float4 f0 = *(const float4*)src;
        float4 f1 = *(const float4*)(src + 4);
        float tmp[8] = {f0.x, f0.y, f0.z, f0.w, f1.x, f1.y, f1.z, f1.w};
        half8v hv, lv;
        #pragma unroll
        for (int e = 0; e < 8; ++e) {
            _Float16 hi = (_Float16)tmp[e];
            hv[e] = hi;
            lv[e] = (_Float16)(tmp[e] - (float)hi);
        }
        size_t dst = ((gbase + g) * 4 + hbase + hh) * (size_t)512 + lf * 8;
        *(half8v*)(oh + dst) = hv;
        *(half8v*)(ol + dst) = lv;
    }
}

// Exact top-32 of a 512-wide half-row in sc (8 values/lane). Returns per-lane winner key (0 = loser).
__device__ __forceinline__ unsigned long long select_pass32(
    const float* R, int ubase, int l, unsigned long long* candw)
{
    float4 vv0 = *(const float4*)(R + l * 4);
    float4 vv1 = *(const float4*)(R + 256 + l * 4);
    float elems[8] = {vv0.x, vv0.y, vv0.z, vv0.w, vv1.x, vv1.y, vv1.z, vv1.w};

    float m = elems[0];
    #pragma unroll
    for (int s = 1; s < 8; ++s) m = fmaxf(m, elems[s]);

    // T = 32nd-largest lane-max via bitwise ballot search
    unsigned km = key_hi_u(m);
    unsigned accT = 0u;
    #pragma unroll
    for (int bit = 31; bit >= 0; --bit) {
        unsigned trial = accT | (1u << bit);
        if (__popcll(__ballot(km >= trial)) >= 32) accT = trial;
    }
    const float T = key_val(accT);   // >= 32 half-row elements are >= T

    candw[l] = 0ull;
    __builtin_amdgcn_wave_barrier();
    int total = 0;
    #pragma unroll
    for (int s = 0; s < 8; ++s) {
        float v = elems[s];
        bool p = (v >= T);
        unsigned long long msk = __ballot(p);
        if (p) {
            int pos = total + __popcll(msk & ((1ull << l) - 1ull));
            if (pos < 64) candw[pos] = make_key(v, ubase + (s >> 2) * 256 + l * 4 + (s & 3));
        }
        total += (int)__popcll(msk);
    }
    __builtin_amdgcn_wave_barrier();

    if (total <= 64) {
        unsigned long long key = candw[l];
        unsigned hi = (unsigned)(key >> 32), lo = (unsigned)key;
        unsigned X = 0u;
        #pragma unroll
        for (int bit = 31; bit >= 0; --bit) {
            unsigned trial = X | (1u << bit);
            if (__popcll(__ballot(hi >= trial)) >= 32) X = trial;
        }
        int cgt = __popcll(__ballot(hi > X));
        int rem = 32 - cgt;
        unsigned Y = 0u;
        #pragma unroll
        for (int bit = 9; bit >= 0; --bit) {
            unsigned trial = Y | (1u << bit);
            if (__popcll(__ballot(hi == X && lo >= trial)) >= rem) Y = trial;
        }
        bool win = (hi > X) || (hi == X && lo >= Y);   // exactly 32 winners
        return win ? key : 0ull;
    } else {
        // rare fallback: exact 32-round butterfly extraction over 8 slots/lane
        float vals[8];
        #pragma unroll
        for (int s = 0; s < 8; ++s) vals[s] = elems[s];
        float selv = 0.f; int seli = 0;
        #pragma unroll 1
        for (int it = 0; it < 32; ++it) {
            float bv = -3.4e38f; int bi = 0x7fffffff;
            #pragma unroll
            for (int s = 0; s < 8; ++s) {
                int lu = (s >> 2) * 256 + l * 4 + (s & 3);
                if (vals[s] > bv) { bv = vals[s]; bi = lu; }
            }
            #pragma unroll
            for (int off = 1; off < 64; off <<= 1) {
                float ov = __shfl_xor(bv, off, 64);
                int oi = __shfl_xor(bi, off, 64);
                if (ov > bv || (ov == bv && oi < bi)) { bv = ov; bi = oi; }
            }
            if (l == it) { selv = bv; seli = bi; }
            if (((bi >> 2) & 63) == l) {
                int slot = ((bi >> 8) << 2) + (bi & 3);
                #pragma unroll
                for (int s = 0; s < 8; ++s) if (s == slot) vals[s] = -3.4e38f;
            }
        }
        return (l < 32) ? make_key(selv, ubase + seli) : 0ull;
    }
}

// ---------------- Kernel 2: fused MFMA scores (2 u-passes) + exact top-32 + row write ----------------
// Block: 16 n-rows x 1024 u, 512 threads. Winner keys held in registers (one slot per pass);
// final merge = X/Y ballot rank over the two slots. b = blk&7 -> per-XCD batch affinity.
__global__ __launch_bounds__(512, 4) void scores_topk(
    const _Float16* __restrict__ qfh, const _Float16* __restrict__ qfl,
    const _Float16* __restrict__ kfh, const _Float16* __restrict__ kfl,
    const float* __restrict__ mlpw, const float* __restrict__ mlpb,
    float* __restrict__ adj)
{
    __shared__ float sc[16 * SROW2];             // 33.0 KB half-row scores
    __shared__ unsigned long long cand[8][64];   // 4 KB

    const int t = threadIdx.x;
    const int blk = blockIdx.x;
    const int b = blk & 7;                       // batch == XCD affinity (k stays L2-hot)
    const int gq = blk >> 3;                     // q row-group (16 rows)

    const int w = t >> 6, l = t & 63;
    const int quad = l >> 4, lane16 = l & 15;

    // A fragments: coalesced 16B loads from fragment-layout q
    half8v Ah[4], Al[4];
    #pragma unroll
    for (int h = 0; h < 4; ++h) {
        size_t a = (((size_t)b * QGROUPS + gq) * 4 + h) * 512 + l * 8;
        Ah[h] = *(const half8v*)(qfh + a);
        Al[h] = *(const half8v*)(qfl + a);
    }

    // wave-uniform MLP constants -> SGPRs (frees ~20 VGPRs)
    float mw[4][4], mb4[4];
    #pragma unroll
    for (int o = 0; o < 4; ++o) {
        mb4[o] = uload(mlpb + o);
        #pragma unroll
        for (int h = 0; h < 4; ++h) mw[o][h] = uload(mlpw + o * 4 + h);
    }
    const float INV = 0.17677669529663687f;      // 1/sqrt(32)

    unsigned long long keyslot[2];               // per-lane winner key per pass (2 rows interleave below)
    unsigned long long keyrow2[2][2];            // [rr][pass]

    #pragma unroll 1
    for (int pass = 0; pass < 2; ++pass) {
        #pragma unroll 2
        for (int i = 0; i < 4; ++i) {
            const int g = pass * 32 + w * 4 + i;
            float4v C[4];
            #pragma unroll
            for (int h = 0; h < 4; ++h) {
                size_t a = (((size_t)b * KGROUPS + g) * 4 + h) * 512 + l * 8;
                half8v Bh = *(const half8v*)(kfh + a);
                half8v Bl = *(const half8v*)(kfl + a);
                float4v c = {0.f, 0.f, 0.f, 0.f};
                c = __builtin_amdgcn_mfma_f32_16x16x32_f16(Ah[h], Bh, c, 0, 0, 0);
                c = __builtin_amdgcn_mfma_f32_16x16x32_f16(Ah[h], Bl, c, 0, 0, 0);
                c = __builtin_amdgcn_mfma_f32_16x16x32_f16(Al[h], Bh, c, 0, 0, 0);
                C[h] = c;
            }
            #pragma unroll
            for (int r = 0; r < 4; ++r) {
                float a0 = C[0][r] * INV, a1 = C[1][r] * INV;
                float a2 = C[2][r] * INV, a3 = C[3][r] * INV;
                float ssum = a0 + a1 + a2 + a3;
                #pragma unroll
                for (int o = 0; o < 4; ++o) {
                    float to = mw[o][0] * a0 + mw[o][1] * a1 + mw[o][2] * a2 + mw[o][3] * a3 + mb4[o];
                    ssum += fmaxf(to, 0.f);
                }
                sc[(quad * 4 + r) * SROW2 + (w * 4 + i) * 16 + lane16] = ssum;
            }
        }
        __syncthreads();                          // half-row scores complete

        for (int rr = 0; rr < 2; ++rr) {
            const int row = w * 2 + rr;
            keyrow2[rr][pass] = select_pass32(sc + row * SROW2, pass * 512, l, cand[w]);
        }
        if (pass == 0) __syncthreads();           // sc reads done before pass-1 overwrites
    }
    (void)keyslot;

    // ---- merge: exact top-32 of the 2x32 winner keys (2 slots/lane); rebuild + write ----
    for (int rr = 0; rr < 2; ++rr) {
        const int row = w * 2 + rr;
        unsigned long long k0 = keyrow2[rr][0], k1 = keyrow2[rr][1];
        unsigned hi0 = (unsigned)(k0 >> 32), lo0 = (unsigned)k0;
        unsigned hi1 = (unsigned)(k1 >> 32), lo1 = (unsigned)k1;

        unsigned X = 0u;
        #pragma unroll
        for (int bit = 31; bit >= 0; --bit) {
            unsigned trial = X | (1u << bit);
            int cnt = __popcll(__ballot(k0 != 0ull && hi0 >= trial)) +
                      __popcll(__ballot(k1 != 0ull && hi1 >= trial));
            if (cnt >= 32) X = trial;
        }
        int cgt = __popcll(__ballot(k0 != 0ull && hi0 > X)) +
                  __popcll(__ballot(k1 != 0ull && hi1 > X));
        int rem = 32 - cgt;
        unsigned Y = 0u;
        #pragma unroll
        for (int bit = 9; bit >= 0; --bit) {
            unsigned trial = Y | (1u << bit);
            int cnt = __popcll(__ballot(k0 != 0ull && hi0 == X && lo0 >= trial)) +
                      __popcll(__ballot(k1 != 0ull && hi1 == X && lo1 >= trial));
            if (cnt >= rem) Y = trial;
        }
        const bool win0 = k0 != 0ull && (hi0 > X || (hi0 == X && lo0 >= Y));
        const bool win1 = k1 != 0ull && (hi1 > X || (hi1 == X && lo1 >= Y));

        float* R = sc + row * SROW2;
        float* rowptr = adj + ((size_t)(b * NODES + gq * 16 + row)) * NODES;
        const float4 z4 = make_float4(0.f, 0.f, 0.f, 0.f);

        // half 0: cols [0, 512)  (pass-0 winners have widx < 512)
        __builtin_amdgcn_wave_barrier();
        *(float4*)(R + l * 4) = z4;
        *(float4*)(R + 256 + l * 4) = z4;
        __builtin_amdgcn_wave_barrier();
        if (win0) R[1023 - (int)lo0] = key_val(hi0);
        __builtin_amdgcn_wave_barrier();
        #pragma unroll
        for (int jj = 0; jj < 2; ++jj)
            *(float4*)(rowptr + jj * 256 + l * 4) = *(const float4*)(R + jj * 256 + l * 4);

        // half 1: cols [512, 1024)  (pass-1 winners have widx >= 512)
        __builtin_amdgcn_wave_barrier();
        *(float4*)(R + l * 4) = z4;
        *(float4*)(R + 256 + l * 4) = z4;
        __builtin_amdgcn_wave_barrier();
        if (win1) R[1023 - (int)lo1 - 512] = key_val(hi1);
        __builtin_amdgcn_wave_barrier();
        #pragma unroll
        for (int jj = 0; jj < 2; ++jj)
            *(float4*)(rowptr + 512 + jj * 256 + l * 4) = *(const float4*)(R + jj * 256 + l * 4);

        // cols [1024, 2048) are always zero
        #pragma unroll
        for (int jj = 0; jj < 4; ++jj)
            *(float4*)(rowptr + 1024 + jj * 256 + l * 4) = z4;
    }
}

extern "C" void kernel_launch(void* const* d_in, const int* in_sizes, int n_in,
                              void* d_out, int out_size, void* d_ws, size_t ws_size,
                              hipStream_t stream) {
    const float* x    = (const float*)d_in[0];
    const float* Wq   = (const float*)d_in[1];
    const float* bq   = (const float*)d_in[2];
    const float* Wk   = (const float*)d_in[3];
    const float* bk   = (const float*)d_in[4];
    const float* mlpw = (const float*)d_in[5];
    const float* mlpb = (const float*)d_in[6];
    // ln_g, ln_b feed only the deleted adj_static -> unused.

    _Float16* qfh = (_Float16*)d_ws;                        // 4 MB
    _Float16* qfl = qfh + (size_t)BATCH * NODES * DTOT;     // 4 MB
    _Float16* kfh = qfl + (size_t)BATCH * NODES * DTOT;     // 2 MB
    _Float16* kfl = kfh + (size_t)BATCH * NKEY * DTOT;      // 2 MB (total 12 MB)
    float* adj = (float*)d_out;

    proj_qk<<<dim3(BATCH * 96), dim3(256), 0, stream>>>(x, Wq, bq, Wk, bk, qfh, qfl, kfh, kfl);
    scores_topk<<<dim3(BATCH * QGROUPS), dim3(512), 0, stream>>>(qfh, qfl, kfh, kfl, mlpw, mlpb, adj);
}

// Round 10
// 202.905 us; speedup vs baseline: 1.0786x; 1.0630x over previous
//
#include <hip/hip_runtime.h>
#include <cstdint>
#include <cstddef>

#define BATCH 8
#define NODES 2048
#define IN_DIM 64
#define DTOT 128
#define NKEY 1024
#define QGROUPS 128    // 2048/16 row-groups per batch
#define KGROUPS 64     // 1024/16 u-groups per batch
#define SROW 1028      // score LDS row stride (f32): 2-way bank aliasing only (free)

typedef _Float16 half8v __attribute__((ext_vector_type(8)));
typedef float float4v __attribute__((ext_vector_type(4)));

__device__ __forceinline__ unsigned long long make_key(float v, int idx) {
    unsigned u = __float_as_uint(v);
    u = (u & 0x80000000u) ? ~u : (u | 0x80000000u);
    return ((unsigned long long)u << 32) | (unsigned)(1023 - idx);
}

__device__ __forceinline__ float key_val(unsigned hi) {
    return __uint_as_float((hi & 0x80000000u) ? (hi & 0x7fffffffu) : ~hi);
}

// ---------------- Kernel 1: projection -> split-fp16 planes in MFMA-fragment layout ----------------
// Fragment layout: plane[b][g][h][l][e], flat = ((bG + g)*4 + h)*512 + l*8 + e
__global__ __launch_bounds__(256) void proj_qk(
    const float* __restrict__ x, const float* __restrict__ Wq, const float* __restrict__ bq,
    const float* __restrict__ Wk, const float* __restrict__ bk,
    _Float16* __restrict__ qfh, _Float16* __restrict__ qfl,
    _Float16* __restrict__ kfh, _Float16* __restrict__ kfl)
{
    __shared__ float xs[64 * 68];
    __shared__ float wsh[64 * 68];

    const int t = threadIdx.x;
    const int blk = blockIdx.x;
    const int b = blk / 96;
    const int idx = blk - b * 96;

    const float* W; const float* bias;
    _Float16* oh; _Float16* ol;
    int nbase, cbase; size_t gbase;
    if (idx < 64) {
        int nt = idx >> 1, ct = idx & 1;
        nbase = nt * 64; cbase = ct * 64;
        W = Wq; bias = bq; oh = qfh; ol = qfl;
        gbase = (size_t)b * QGROUPS + (nbase >> 4);
    } else {
        int i2 = idx - 64;
        int nt = i2 >> 1, ct = i2 & 1;
        nbase = nt * 64; cbase = ct * 64;
        W = Wk; bias = bk; oh = kfh; ol = kfl;
        gbase = (size_t)b * KGROUPS + (nbase >> 4);
    }
    const int hbase = cbase >> 5;

    #pragma unroll
    for (int rep = 0; rep < 4; ++rep) {
        int f = rep * 256 + t;
        int r = f >> 4, d4 = f & 15;
        float4 xv = *(const float4*)(x + ((size_t)(b * NODES + nbase + r)) * IN_DIM + d4 * 4);
        *(float4*)(xs + r * 68 + d4 * 4) = xv;
        float4 wv = *(const float4*)(W + (size_t)(cbase + r) * IN_DIM + d4 * 4);
        *(float4*)(wsh + r * 68 + d4 * 4) = wv;
    }
    __syncthreads();

    const int w = t >> 6, l = t & 63;
    const int n_sel = w * 4 + (l >> 4);
    const int ul = l & 15;

    float acc[4][4];
    #pragma unroll
    for (int i = 0; i < 4; ++i)
        #pragma unroll
        for (int j = 0; j < 4; ++j) acc[i][j] = 0.f;

    #pragma unroll
    for (int d4 = 0; d4 < 16; ++d4) {
        float4 xv[4], wv[4];
        #pragma unroll
        for (int i = 0; i < 4; ++i)
            xv[i] = *(const float4*)(xs + (n_sel * 4 + i) * 68 + d4 * 4);
        #pragma unroll
        for (int j = 0; j < 4; ++j)
            wv[j] = *(const float4*)(wsh + (j * 16 + ul) * 68 + d4 * 4);
        #pragma unroll
        for (int i = 0; i < 4; ++i)
            #pragma unroll
            for (int j = 0; j < 4; ++j)
                acc[i][j] += xv[i].x * wv[j].x + xv[i].y * wv[j].y +
                             xv[i].z * wv[j].z + xv[i].w * wv[j].w;
    }
    __syncthreads();   // reuse xs as the 64x64 fp32 result tile

    #pragma unroll
    for (int j = 0; j < 4; ++j) {
        float bv = bias[cbase + j * 16 + ul];
        #pragma unroll
        for (int i = 0; i < 4; ++i)
            xs[(n_sel * 4 + i) * 68 + j * 16 + ul] = acc[i][j] + bv;
    }
    __syncthreads();

    #pragma unroll
    for (int rep = 0; rep < 2; ++rep) {
        int u = rep * 256 + t;
        int g = u >> 7, hh = (u >> 6) & 1, lf = u & 63;
        const float* src = xs + (g * 16 + (lf & 15)) * 68 + hh * 32 + (lf >> 4) * 8;
        float4 f0 = *(const float4*)src;
        float4 f1 = *(const float4*)(src + 4);
        float tmp[8] = {f0.x, f0.y, f0.z, f0.w, f1.x, f1.y, f1.z, f1.w};
        half8v hv, lv;
        #pragma unroll
        for (int e = 0; e < 8; ++e) {
            _Float16 hi = (_Float16)tmp[e];
            hv[e] = hi;
            lv[e] = (_Float16)(tmp[e] - (float)hi);
        }
        size_t dst = ((gbase + g) * 4 + hbase + hh) * (size_t)512 + lf * 8;
        *(half8v*)(oh + dst) = hv;
        *(half8v*)(ol + dst) = lv;
    }
}

// ---------------- Kernel 2: MFMA scores + ballot top-32 -> compact (val, idx) lists ----------------
// Exact R7 structure (single pass, 16 u-groups/wave) minus the row rebuild/stream-out.
__global__ __launch_bounds__(512, 4) void scores_sel(
    const _Float16* __restrict__ qfh, const _Float16* __restrict__ qfl,
    const _Float16* __restrict__ kfh, const _Float16* __restrict__ kfl,
    const float* __restrict__ mlpw, const float* __restrict__ mlpb,
    float* __restrict__ kval, int* __restrict__ kidx)
{
    __shared__ float sc[16 * SROW];            // 64.25 KB scores
    __shared__ unsigned long long cand[8][64]; // 4 KB candidate buffers

    const int t = threadIdx.x;
    const int blk = blockIdx.x;
    const int b = blk & 7;                     // batch == XCD affinity (k stays L2-hot)
    const int gq = blk >> 3;                   // q row-group (16 rows)

    const int w = t >> 6, l = t & 63;
    const int quad = l >> 4, lane16 = l & 15;

    // A fragments: coalesced 16B loads from fragment-layout q
    half8v Ah[4], Al[4];
    #pragma unroll
    for (int h = 0; h < 4; ++h) {
        size_t a = (((size_t)b * QGROUPS + gq) * 4 + h) * 512 + l * 8;
        Ah[h] = *(const half8v*)(qfh + a);
        Al[h] = *(const half8v*)(qfl + a);
    }

    float mw[4][4], mb4[4];
    #pragma unroll
    for (int o = 0; o < 4; ++o) {
        mb4[o] = mlpb[o];
        #pragma unroll
        for (int h = 0; h < 4; ++h) mw[o][h] = mlpw[o * 4 + h];
    }
    const float INV = 0.17677669529663687f;    // 1/sqrt(32)

    #pragma unroll 2
    for (int i = 0; i < 8; ++i) {
        const int g = w * 8 + i;               // u-group
        float4v C[4];
        #pragma unroll
        for (int h = 0; h < 4; ++h) {
            size_t a = (((size_t)b * KGROUPS + g) * 4 + h) * 512 + l * 8;
            half8v Bh = *(const half8v*)(kfh + a);
            half8v Bl = *(const half8v*)(kfl + a);
            float4v c = {0.f, 0.f, 0.f, 0.f};
            c = __builtin_amdgcn_mfma_f32_16x16x32_f16(Ah[h], Bh, c, 0, 0, 0);
            c = __builtin_amdgcn_mfma_f32_16x16x32_f16(Ah[h], Bl, c, 0, 0, 0);
            c = __builtin_amdgcn_mfma_f32_16x16x32_f16(Al[h], Bh, c, 0, 0, 0);
            C[h] = c;
        }
        #pragma unroll
        for (int r = 0; r < 4; ++r) {
            float a0 = C[0][r] * INV, a1 = C[1][r] * INV;
            float a2 = C[2][r] * INV, a3 = C[3][r] * INV;
            float ssum = a0 + a1 + a2 + a3;
            #pragma unroll
            for (int o = 0; o < 4; ++o) {
                float to = mw[o][0] * a0 + mw[o][1] * a1 + mw[o][2] * a2 + mw[o][3] * a3 + mb4[o];
                ssum += fmaxf(to, 0.f);
            }
            sc[(quad * 4 + r) * SROW + g * 16 + lane16] = ssum;
        }
    }
    __syncthreads();

    // ---- top-32 per row; wave w handles rows 2w, 2w+1; ranking via ballot ----
    for (int rr = 0; rr < 2; ++rr) {
        const int row = w * 2 + rr;
        const float* R = sc + row * SROW;
        const size_t grow = (size_t)(b * NODES + gq * 16 + row);

        float4 vv[4];   // lane l holds u-indices jj*256 + l*4 + e
        #pragma unroll
        for (int jj = 0; jj < 4; ++jj) vv[jj] = *(const float4*)(R + jj * 256 + l * 4);

        float m = vv[0].x;
        #pragma unroll
        for (int jj = 0; jj < 4; ++jj) {
            m = fmaxf(m, vv[jj].x); m = fmaxf(m, vv[jj].y);
            m = fmaxf(m, vv[jj].z); m = fmaxf(m, vv[jj].w);
        }

        // T = 32nd-largest lane-max, exact, via bitwise ballot search
        unsigned km;
        { unsigned s = __float_as_uint(m); km = (s & 0x80000000u) ? ~s : (s | 0x80000000u); }
        unsigned accT = 0u;
        #pragma unroll
        for (int bit = 31; bit >= 0; --bit) {
            unsigned trial = accT | (1u << bit);
            if (__popcll(__ballot(km >= trial)) >= 32) accT = trial;
        }
        const float T = key_val(accT);   // >= 32 row elements are >= T

        // ballot-compact candidates >= T into cand[w][]
        cand[w][l] = 0ull;
        __builtin_amdgcn_wave_barrier();
        int total = 0;
        #pragma unroll
        for (int jj = 0; jj < 4; ++jj) {
            #pragma unroll
            for (int e = 0; e < 4; ++e) {
                float v = (e == 0) ? vv[jj].x : (e == 1) ? vv[jj].y : (e == 2) ? vv[jj].z : vv[jj].w;
                bool p = (v >= T);
                unsigned long long msk = __ballot(p);
                if (p) {
                    int pos = total + __popcll(msk & ((1ull << l) - 1ull));
                    if (pos < 64) cand[w][pos] = make_key(v, jj * 256 + l * 4 + e);
                }
                total += (int)__popcll(msk);
            }
        }
        __builtin_amdgcn_wave_barrier();

        if (total <= 64) {
            unsigned long long key = cand[w][l];   // one key per lane (0 = empty, sorts last)
            unsigned hi = (unsigned)(key >> 32), lo = (unsigned)key;

            unsigned X = 0u;
            #pragma unroll
            for (int bit = 31; bit >= 0; --bit) {
                unsigned trial = X | (1u << bit);
                if (__popcll(__ballot(hi >= trial)) >= 32) X = trial;
            }
            int cgt = __popcll(__ballot(hi > X));
            int rem = 32 - cgt;
            unsigned Y = 0u;
            #pragma unroll
            for (int bit = 9; bit >= 0; --bit) {
                unsigned trial = Y | (1u << bit);
                if (__popcll(__ballot(hi == X && lo >= trial)) >= rem) Y = trial;
            }
            const bool win = (hi > X) || (hi == X && lo >= Y);   // exactly 32 winners
            unsigned long long wm = __ballot(win);
            if (win) {
                int pos = __popcll(wm & ((1ull << l) - 1ull));
                kval[grow * 32 + pos] = key_val(hi);
                kidx[grow * 32 + pos] = 1023 - (int)lo;
            }
        } else {
            // rare fallback: exact 32-round butterfly extraction
            float vals[16];
            #pragma unroll
            for (int jj = 0; jj < 4; ++jj) {
                vals[jj * 4 + 0] = vv[jj].x; vals[jj * 4 + 1] = vv[jj].y;
                vals[jj * 4 + 2] = vv[jj].z; vals[jj * 4 + 3] = vv[jj].w;
            }
            float selv = 0.f; int seli = 0;
            #pragma unroll 1
            for (int it = 0; it < 32; ++it) {
                float bv = -3.4e38f; int bi = 0x7fffffff;
                #pragma unroll
                for (int s = 0; s < 16; ++s) {
                    int idx2 = (s >> 2) * 256 + l * 4 + (s & 3);
                    if (vals[s] > bv) { bv = vals[s]; bi = idx2; }
                }
                #pragma unroll
                for (int off = 1; off < 64; off <<= 1) {
                    float ov = __shfl_xor(bv, off, 64);
                    int oi = __shfl_xor(bi, off, 64);
                    if (ov > bv || (ov == bv && oi < bi)) { bv = ov; bi = oi; }
                }
                if (l == it) { selv = bv; seli = bi; }
                if (((bi >> 2) & 63) == l) {
                    int slot = ((bi >> 8) << 2) + (bi & 3);
                    #pragma unroll
                    for (int s = 0; s < 16; ++s) if (s == slot) vals[s] = -3.4e38f;
                }
            }
            if (l < 32) {
                kval[grow * 32 + l] = selv;
                kidx[grow * 32 + l] = seli;
            }
        }
    }
}

// ---------------- Kernel 3: streaming adjacency write (2 rows/block, pure write-bound) ----------------
__global__ __launch_bounds__(256) void write_adj(
    const float* __restrict__ kval, const int* __restrict__ kidx,
    float* __restrict__ adj)
{
    __shared__ float rowbuf[2 * 1024];   // 8 KB

    const int t = threadIdx.x;
    const int row0 = blockIdx.x * 2;

    // zero the two 1024-wide lower halves (2048 floats = 512 float4)
    #pragma unroll
    for (int i = 0; i < 2; ++i)
        *(float4*)(&rowbuf[(i * 256 + t) * 4]) = make_float4(0.f, 0.f, 0.f, 0.f);
    __syncthreads();

    // scatter: wave 0 (t<64) handles 2 rows x 32 entries
    if (t < 64) {
        int r = t >> 5, j = t & 31;
        size_t src = (size_t)(row0 + r) * 32 + j;
        rowbuf[r * 1024 + kidx[src]] = kval[src];
    }
    __syncthreads();

    // stream out: 2 rows x 2048 floats; upper halves are zero
    const float4 z4 = make_float4(0.f, 0.f, 0.f, 0.f);
    #pragma unroll
    for (int r = 0; r < 2; ++r) {
        float* rp = adj + (size_t)(row0 + r) * NODES;
        *(float4*)(rp + t * 4) = *(const float4*)(&rowbuf[r * 1024 + t * 4]);
        *(float4*)(rp + 1024 + t * 4) = z4;
    }
}

extern "C" void kernel_launch(void* const* d_in, const int* in_sizes, int n_in,
                              void* d_out, int out_size, void* d_ws, size_t ws_size,
                              hipStream_t stream) {
    const float* x    = (const float*)d_in[0];
    const float* Wq   = (const float*)d_in[1];
    const float* bq   = (const float*)d_in[2];
    const float* Wk   = (const float*)d_in[3];
    const float* bk   = (const float*)d_in[4];
    const float* mlpw = (const float*)d_in[5];
    const float* mlpb = (const float*)d_in[6];
    // ln_g, ln_b feed only the deleted adj_static -> unused.

    _Float16* qfh = (_Float16*)d_ws;                        // 4 MB
    _Float16* qfl = qfh + (size_t)BATCH * NODES * DTOT;     // 4 MB
    _Float16* kfh = qfl + (size_t)BATCH * NODES * DTOT;     // 2 MB
    _Float16* kfl = kfh + (size_t)BATCH * NKEY * DTOT;      // 2 MB (total 12 MB)
    float* kval = (float*)(kfl + (size_t)BATCH * NKEY * DTOT);   // 16384*32 f32 = 2 MB
    int*   kidx = (int*)(kval + (size_t)BATCH * NODES * 32);     // 2 MB
    float* adj = (float*)d_out;

    proj_qk<<<dim3(BATCH * 96), dim3(256), 0, stream>>>(x, Wq, bq, Wk, bk, qfh, qfl, kfh, kfl);
    scores_sel<<<dim3(BATCH * QGROUPS), dim3(512), 0, stream>>>(qfh, qfl, kfh, kfl, mlpw, mlpb, kval, kidx);
    write_adj<<<dim3(BATCH * NODES / 2), dim3(256), 0, stream>>>(kval, kidx, adj);
}

// Round 11
// 188.238 us; speedup vs baseline: 1.1626x; 1.0779x over previous
//
#include <hip/hip_runtime.h>
#include <cstdint>
#include <cstddef>

#define BATCH 8
#define NODES 2048
#define IN_DIM 64
#define DTOT 128
#define NKEY 1024
#define QGROUPS 128    // 2048/16 row-groups per batch
#define KGROUPS 64     // 1024/16 u-groups per batch
#define SROW 1028      // score LDS row stride (f32): 2-way bank aliasing only (free)

typedef _Float16 half8v __attribute__((ext_vector_type(8)));
typedef float float4v __attribute__((ext_vector_type(4)));
typedef float float2v __attribute__((ext_vector_type(2)));

__device__ __forceinline__ unsigned long long make_key(float v, int idx) {
    unsigned u = __float_as_uint(v);
    u = (u & 0x80000000u) ? ~u : (u | 0x80000000u);
    return ((unsigned long long)u << 32) | (unsigned)(1023 - idx);
}

__device__ __forceinline__ float key_val(unsigned hi) {
    return __uint_as_float((hi & 0x80000000u) ? (hi & 0x7fffffffu) : ~hi);
}

// ---------------- Kernel 1: projection -> split-fp16 planes in MFMA-fragment layout ----------------
// Fragment layout: plane[b][g][h][l][e], flat = ((bG + g)*4 + h)*512 + l*8 + e
// q is pre-scaled by 1/sqrt(32) (k by 1.0 -> bit-exact) so the score epilogue drops 4 muls/elem.
__global__ __launch_bounds__(256) void proj_qk(
    const float* __restrict__ x, const float* __restrict__ Wq, const float* __restrict__ bq,
    const float* __restrict__ Wk, const float* __restrict__ bk,
    _Float16* __restrict__ qfh, _Float16* __restrict__ qfl,
    _Float16* __restrict__ kfh, _Float16* __restrict__ kfl)
{
    __shared__ float xs[64 * 68];
    __shared__ float wsh[64 * 68];

    const int t = threadIdx.x;
    const int blk = blockIdx.x;
    const int b = blk / 96;
    const int idx = blk - b * 96;

    const float* W; const float* bias;
    _Float16* oh; _Float16* ol;
    int nbase, cbase; size_t gbase;
    float scale;
    if (idx < 64) {
        int nt = idx >> 1, ct = idx & 1;
        nbase = nt * 64; cbase = ct * 64;
        W = Wq; bias = bq; oh = qfh; ol = qfl;
        gbase = (size_t)b * QGROUPS + (nbase >> 4);
        scale = 0.17677669529663687f;   // 1/sqrt(32)
    } else {
        int i2 = idx - 64;
        int nt = i2 >> 1, ct = i2 & 1;
        nbase = nt * 64; cbase = ct * 64;
        W = Wk; bias = bk; oh = kfh; ol = kfl;
        gbase = (size_t)b * KGROUPS + (nbase >> 4);
        scale = 1.0f;                   // exact no-op for k
    }
    const int hbase = cbase >> 5;

    #pragma unroll
    for (int rep = 0; rep < 4; ++rep) {
        int f = rep * 256 + t;
        int r = f >> 4, d4 = f & 15;
        float4 xv = *(const float4*)(x + ((size_t)(b * NODES + nbase + r)) * IN_DIM + d4 * 4);
        *(float4*)(xs + r * 68 + d4 * 4) = xv;
        float4 wv = *(const float4*)(W + (size_t)(cbase + r) * IN_DIM + d4 * 4);
        *(float4*)(wsh + r * 68 + d4 * 4) = wv;
    }
    __syncthreads();

    const int w = t >> 6, l = t & 63;
    const int n_sel = w * 4 + (l >> 4);
    const int ul = l & 15;

    float acc[4][4];
    #pragma unroll
    for (int i = 0; i < 4; ++i)
        #pragma unroll
        for (int j = 0; j < 4; ++j) acc[i][j] = 0.f;

    #pragma unroll
    for (int d4 = 0; d4 < 16; ++d4) {
        float4 xv[4], wv[4];
        #pragma unroll
        for (int i = 0; i < 4; ++i)
            xv[i] = *(const float4*)(xs + (n_sel * 4 + i) * 68 + d4 * 4);
        #pragma unroll
        for (int j = 0; j < 4; ++j)
            wv[j] = *(const float4*)(wsh + (j * 16 + ul) * 68 + d4 * 4);
        #pragma unroll
        for (int i = 0; i < 4; ++i)
            #pragma unroll
            for (int j = 0; j < 4; ++j)
                acc[i][j] += xv[i].x * wv[j].x + xv[i].y * wv[j].y +
                             xv[i].z * wv[j].z + xv[i].w * wv[j].w;
    }
    __syncthreads();   // reuse xs as the 64x64 fp32 result tile

    #pragma unroll
    for (int j = 0; j < 4; ++j) {
        float bv = bias[cbase + j * 16 + ul];
        #pragma unroll
        for (int i = 0; i < 4; ++i)
            xs[(n_sel * 4 + i) * 68 + j * 16 + ul] = (acc[i][j] + bv) * scale;
    }
    __syncthreads();

    #pragma unroll
    for (int rep = 0; rep < 2; ++rep) {
        int u = rep * 256 + t;
        int g = u >> 7, hh = (u >> 6) & 1, lf = u & 63;
        const float* src = xs + (g * 16 + (lf & 15)) * 68 + hh * 32 + (lf >> 4) * 8;
        float4 f0 = *(const float4*)src;
        float4 f1 = *(const float4*)(src + 4);
        float tmp[8] = {f0.x, f0.y, f0.z, f0.w, f1.x, f1.y, f1.z, f1.w};
        half8v hv, lv;
        #pragma unroll
        for (int e = 0; e < 8; ++e) {
            _Float16 hi = (_Float16)tmp[e];
            hv[e] = hi;
            lv[e] = (_Float16)(tmp[e] - (float)hi);
        }
        size_t dst = ((gbase + g) * 4 + hbase + hh) * (size_t)512 + lf * 8;
        *(half8v*)(oh + dst) = hv;
        *(half8v*)(ol + dst) = lv;
    }
}

// ---------------- Kernel 2: fused MFMA scores + ballot top-32 + final row write (R7 base) ----------------
// Block: 16 n-rows x 1024 u, 512 threads (8 waves). Wave w: u-strip [w*128, w*128+128) in the
// score phase, rows {2w, 2w+1} in the select phase. b = blk&7 -> per-XCD batch affinity.
__global__ __launch_bounds__(512, 4) void scores_topk(
    const _Float16* __restrict__ qfh, const _Float16* __restrict__ qfl,
    const _Float16* __restrict__ kfh, const _Float16* __restrict__ kfl,
    const float* __restrict__ mlpw, const float* __restrict__ mlpb,
    float* __restrict__ adj)
{
    __shared__ float sc[16 * SROW];            // 64.25 KB scores
    __shared__ unsigned long long cand[8][64]; // 4 KB candidate buffers

    const int t = threadIdx.x;
    const int blk = blockIdx.x;
    const int b = blk & 7;                     // batch == XCD affinity (k stays L2-hot)
    const int gq = blk >> 3;                   // q row-group (16 rows)

    const int w = t >> 6, l = t & 63;
    const int quad = l >> 4, lane16 = l & 15;

    // A fragments: coalesced 16B loads from fragment-layout q
    half8v Ah[4], Al[4];
    #pragma unroll
    for (int h = 0; h < 4; ++h) {
        size_t a = (((size_t)b * QGROUPS + gq) * 4 + h) * 512 + l * 8;
        Ah[h] = *(const half8v*)(qfh + a);
        Al[h] = *(const half8v*)(qfl + a);
    }

    float2v mw2[4][4], mb2[4];
    #pragma unroll
    for (int o = 0; o < 4; ++o) {
        float bvo = mlpb[o];
        mb2[o] = (float2v){bvo, bvo};
        #pragma unroll
        for (int h = 0; h < 4; ++h) {
            float mwo = mlpw[o * 4 + h];
            mw2[o][h] = (float2v){mwo, mwo};
        }
    }
    const float2v z2 = {0.f, 0.f};

    #pragma unroll 2
    for (int i = 0; i < 8; ++i) {
        const int g = w * 8 + i;               // u-group
        float4v C[4];
        #pragma unroll
        for (int h = 0; h < 4; ++h) {
            size_t a = (((size_t)b * KGROUPS + g) * 4 + h) * 512 + l * 8;
            half8v Bh = *(const half8v*)(kfh + a);
            half8v Bl = *(const half8v*)(kfl + a);
            float4v c = {0.f, 0.f, 0.f, 0.f};
            c = __builtin_amdgcn_mfma_f32_16x16x32_f16(Ah[h], Bh, c, 0, 0, 0);
            c = __builtin_amdgcn_mfma_f32_16x16x32_f16(Ah[h], Bl, c, 0, 0, 0);
            c = __builtin_amdgcn_mfma_f32_16x16x32_f16(Al[h], Bh, c, 0, 0, 0);
            C[h] = c;
        }
        // packed epilogue: rows in pairs (v_pk_fma_f32 / v_pk_add_f32 / v_pk_max_f32)
        #pragma unroll
        for (int r2 = 0; r2 < 2; ++r2) {
            float2v a0 = {C[0][2 * r2], C[0][2 * r2 + 1]};
            float2v a1 = {C[1][2 * r2], C[1][2 * r2 + 1]};
            float2v a2 = {C[2][2 * r2], C[2][2 * r2 + 1]};
            float2v a3 = {C[3][2 * r2], C[3][2 * r2 + 1]};
            float2v ssum = ((a0 + a1) + a2) + a3;
            #pragma unroll
            for (int o = 0; o < 4; ++o) {
                float2v to = a0 * mw2[o][0] + a1 * mw2[o][1] +
                             a2 * mw2[o][2] + a3 * mw2[o][3] + mb2[o];
                ssum += __builtin_elementwise_max(to, z2);
            }
            const int col = g * 16 + lane16;
            sc[(quad * 4 + 2 * r2) * SROW + col] = ssum[0];
            sc[(quad * 4 + 2 * r2 + 1) * SROW + col] = ssum[1];
        }
    }
    __syncthreads();

    // ---- top-32 per row; wave w handles rows 2w, 2w+1; ranking via ballot (no DS traffic) ----
    for (int rr = 0; rr < 2; ++rr) {
        const int row = w * 2 + rr;
        float* R = sc + row * SROW;

        float4 vv[4];   // lane l holds u-indices jj*256 + l*4 + e
        #pragma unroll
        for (int jj = 0; jj < 4; ++jj) vv[jj] = *(const float4*)(R + jj * 256 + l * 4);

        float m = vv[0].x;
        #pragma unroll
        for (int jj = 0; jj < 4; ++jj) {
            m = fmaxf(m, vv[jj].x); m = fmaxf(m, vv[jj].y);
            m = fmaxf(m, vv[jj].z); m = fmaxf(m, vv[jj].w);
        }

        // T = 32nd-largest lane-max, exact, via bitwise ballot search (order-preserving uint)
        unsigned km;
        { unsigned s = __float_as_uint(m); km = (s & 0x80000000u) ? ~s : (s | 0x80000000u); }
        unsigned accT = 0u;
        #pragma unroll
        for (int bit = 31; bit >= 0; --bit) {
            unsigned trial = accT | (1u << bit);
            if (__popcll(__ballot(km >= trial)) >= 32) accT = trial;
        }
        const float T = key_val(accT);   // >= 32 row elements are >= T, T <= true 32nd value

        // ballot-compact candidates >= T into cand[w][]
        cand[w][l] = 0ull;
        __builtin_amdgcn_wave_barrier();
        int total = 0;
        #pragma unroll
        for (int jj = 0; jj < 4; ++jj) {
            #pragma unroll
            for (int e = 0; e < 4; ++e) {
                float v = (e == 0) ? vv[jj].x : (e == 1) ? vv[jj].y : (e == 2) ? vv[jj].z : vv[jj].w;
                bool p = (v >= T);
                unsigned long long msk = __ballot(p);
                if (p) {
                    int pos = total + __popcll(msk & ((1ull << l) - 1ull));
                    if (pos < 64) cand[w][pos] = make_key(v, jj * 256 + l * 4 + e);
                }
                total += (int)__popcll(msk);
            }
        }
        __builtin_amdgcn_wave_barrier();

        bool win = false; float wval = 0.f; int widx = 0;
        if (total <= 64) {
            unsigned long long key = cand[w][l];   // one key per lane (0 = empty, sorts last)
            unsigned hi = (unsigned)(key >> 32), lo = (unsigned)key;

            unsigned X = 0u;
            #pragma unroll
            for (int bit = 31; bit >= 0; --bit) {
                unsigned trial = X | (1u << bit);
                if (__popcll(__ballot(hi >= trial)) >= 32) X = trial;
            }
            int cgt = __popcll(__ballot(hi > X));
            int rem = 32 - cgt;
            unsigned Y = 0u;
            #pragma unroll
            for (int bit = 9; bit >= 0; --bit) {
                unsigned trial = Y | (1u << bit);
                if (__popcll(__ballot(hi == X && lo >= trial)) >= rem) Y = trial;
            }
            if (hi > X || (hi == X && lo >= Y)) {   // exactly 32 winners
                win = true;
                wval = key_val(hi);
                widx = 1023 - (int)lo;
            }
        } else {
            // rare fallback: exact 32-round butterfly extraction
            float vals[16];
            #pragma unroll
            for (int jj = 0; jj < 4; ++jj) {
                vals[jj * 4 + 0] = vv[jj].x; vals[jj * 4 + 1] = vv[jj].y;
                vals[jj * 4 + 2] = vv[jj].z; vals[jj * 4 + 3] = vv[jj].w;
            }
            float selv = 0.f; int seli = 0;
            #pragma unroll 1
            for (int it = 0; it < 32; ++it) {
                float bv = -3.4e38f; int bi = 0x7fffffff;
                #pragma unroll
                for (int s = 0; s < 16; ++s) {
                    int idx2 = (s >> 2) * 256 + l * 4 + (s & 3);
                    if (vals[s] > bv) { bv = vals[s]; bi = idx2; }
                }
                #pragma unroll
                for (int off = 1; off < 64; off <<= 1) {
                    float ov = __shfl_xor(bv, off, 64);
                    int oi = __shfl_xor(bi, off, 64);
                    if (ov > bv || (ov == bv && oi < bi)) { bv = ov; bi = oi; }
                }
                if (l == it) { selv = bv; seli = bi; }
                if (((bi >> 2) & 63) == l) {
                    int slot = ((bi >> 8) << 2) + (bi & 3);
                    #pragma unroll
                    for (int s = 0; s < 16; ++s) if (s == slot) vals[s] = -3.4e38f;
                }
            }
            if (l < 32) { win = true; wval = selv; widx = seli; }
        }

        // rebuild the row in place (DS pipe is in-order per wave)
        __builtin_amdgcn_wave_barrier();
        #pragma unroll
        for (int jj = 0; jj < 16; ++jj) R[l + (jj << 6)] = 0.f;
        __builtin_amdgcn_wave_barrier();
        if (win) R[widx] = wval;
        __builtin_amdgcn_wave_barrier();

        // final coalesced write of the 2048-wide row (upper half zeros)
        float* rowptr = adj + ((size_t)(b * NODES + gq * 16 + row)) * NODES;
        #pragma unroll
        for (int jj = 0; jj < 8; ++jj) {
            int c4 = jj * 64 + l;
            float4 val;
            if (c4 < 256) val = *(const float4*)(R + c4 * 4);
            else          val = make_float4(0.f, 0.f, 0.f, 0.f);
            *(float4*)(rowptr + c4 * 4) = val;
        }
    }
}

extern "C" void kernel_launch(void* const* d_in, const int* in_sizes, int n_in,
                              void* d_out, int out_size, void* d_ws, size_t ws_size,
                              hipStream_t stream) {
    const float* x    = (const float*)d_in[0];
    const float* Wq   = (const float*)d_in[1];
    const float* bq   = (const float*)d_in[2];
    const float* Wk   = (const float*)d_in[3];
    const float* bk   = (const float*)d_in[4];
    const float* mlpw = (const float*)d_in[5];
    const float* mlpb = (const float*)d_in[6];
    // ln_g, ln_b feed only the deleted adj_static -> unused.

    _Float16* qfh = (_Float16*)d_ws;                        // 4 MB
    _Float16* qfl = qfh + (size_t)BATCH * NODES * DTOT;     // 4 MB
    _Float16* kfh = qfl + (size_t)BATCH * NODES * DTOT;     // 2 MB
    _Float16* kfl = kfh + (size_t)BATCH * NKEY * DTOT;      // 2 MB (total 12 MB)
    float* adj = (float*)d_out;

    proj_qk<<<dim3(BATCH * 96), dim3(256), 0, stream>>>(x, Wq, bq, Wk, bk, qfh, qfl, kfh, kfl);
    scores_topk<<<dim3(BATCH * QGROUPS), dim3(512), 0, stream>>>(qfh, qfl, kfh, kfl, mlpw, mlpb, adj);
}

// Round 12
// 185.862 us; speedup vs baseline: 1.1775x; 1.0128x over previous
//
#include <hip/hip_runtime.h>
#include <cstdint>
#include <cstddef>

#define BATCH 8
#define NODES 2048
#define IN_DIM 64
#define DTOT 128
#define NKEY 1024
#define QGROUPS 128    // 2048/16 row-groups per batch
#define KGROUPS 64     // 1024/16 u-groups per batch
#define SROW 1028      // score LDS row stride (f32): 2-way bank aliasing only (free)

typedef _Float16 half8v __attribute__((ext_vector_type(8)));
typedef float float4v __attribute__((ext_vector_type(4)));
typedef float float2v __attribute__((ext_vector_type(2)));

__device__ __forceinline__ unsigned long long make_key(float v, int idx) {
    unsigned u = __float_as_uint(v);
    u = (u & 0x80000000u) ? ~u : (u | 0x80000000u);
    return ((unsigned long long)u << 32) | (unsigned)(1023 - idx);
}

__device__ __forceinline__ float key_val(unsigned hi) {
    return __uint_as_float((hi & 0x80000000u) ? (hi & 0x7fffffffu) : ~hi);
}

// ---------------- Kernel 1: projection -> split-fp16 planes in MFMA-fragment layout ----------------
// Fragment layout: plane[b][g][h][l][e], flat = ((bG + g)*4 + h)*512 + l*8 + e
// q is pre-scaled by 1/sqrt(32) (k by 1.0 -> bit-exact) so the score epilogue drops 4 muls/elem.
__global__ __launch_bounds__(256) void proj_qk(
    const float* __restrict__ x, const float* __restrict__ Wq, const float* __restrict__ bq,
    const float* __restrict__ Wk, const float* __restrict__ bk,
    _Float16* __restrict__ qfh, _Float16* __restrict__ qfl,
    _Float16* __restrict__ kfh, _Float16* __restrict__ kfl)
{
    __shared__ float xs[64 * 68];
    __shared__ float wsh[64 * 68];

    const int t = threadIdx.x;
    const int blk = blockIdx.x;
    const int b = blk / 96;
    const int idx = blk - b * 96;

    const float* W; const float* bias;
    _Float16* oh; _Float16* ol;
    int nbase, cbase; size_t gbase;
    float scale;
    if (idx < 64) {
        int nt = idx >> 1, ct = idx & 1;
        nbase = nt * 64; cbase = ct * 64;
        W = Wq; bias = bq; oh = qfh; ol = qfl;
        gbase = (size_t)b * QGROUPS + (nbase >> 4);
        scale = 0.17677669529663687f;   // 1/sqrt(32)
    } else {
        int i2 = idx - 64;
        int nt = i2 >> 1, ct = i2 & 1;
        nbase = nt * 64; cbase = ct * 64;
        W = Wk; bias = bk; oh = kfh; ol = kfl;
        gbase = (size_t)b * KGROUPS + (nbase >> 4);
        scale = 1.0f;                   // exact no-op for k
    }
    const int hbase = cbase >> 5;

    #pragma unroll
    for (int rep = 0; rep < 4; ++rep) {
        int f = rep * 256 + t;
        int r = f >> 4, d4 = f & 15;
        float4 xv = *(const float4*)(x + ((size_t)(b * NODES + nbase + r)) * IN_DIM + d4 * 4);
        *(float4*)(xs + r * 68 + d4 * 4) = xv;
        float4 wv = *(const float4*)(W + (size_t)(cbase + r) * IN_DIM + d4 * 4);
        *(float4*)(wsh + r * 68 + d4 * 4) = wv;
    }
    __syncthreads();

    const int w = t >> 6, l = t & 63;
    const int n_sel = w * 4 + (l >> 4);
    const int ul = l & 15;

    float acc[4][4];
    #pragma unroll
    for (int i = 0; i < 4; ++i)
        #pragma unroll
        for (int j = 0; j < 4; ++j) acc[i][j] = 0.f;

    #pragma unroll
    for (int d4 = 0; d4 < 16; ++d4) {
        float4 xv[4], wv[4];
        #pragma unroll
        for (int i = 0; i < 4; ++i)
            xv[i] = *(const float4*)(xs + (n_sel * 4 + i) * 68 + d4 * 4);
        #pragma unroll
        for (int j = 0; j < 4; ++j)
            wv[j] = *(const float4*)(wsh + (j * 16 + ul) * 68 + d4 * 4);
        #pragma unroll
        for (int i = 0; i < 4; ++i)
            #pragma unroll
            for (int j = 0; j < 4; ++j)
                acc[i][j] += xv[i].x * wv[j].x + xv[i].y * wv[j].y +
                             xv[i].z * wv[j].z + xv[i].w * wv[j].w;
    }
    __syncthreads();   // reuse xs as the 64x64 fp32 result tile

    #pragma unroll
    for (int j = 0; j < 4; ++j) {
        float bv = bias[cbase + j * 16 + ul];
        #pragma unroll
        for (int i = 0; i < 4; ++i)
            xs[(n_sel * 4 + i) * 68 + j * 16 + ul] = (acc[i][j] + bv) * scale;
    }
    __syncthreads();

    #pragma unroll
    for (int rep = 0; rep < 2; ++rep) {
        int u = rep * 256 + t;
        int g = u >> 7, hh = (u >> 6) & 1, lf = u & 63;
        const float* src = xs + (g * 16 + (lf & 15)) * 68 + hh * 32 + (lf >> 4) * 8;
        float4 f0 = *(const float4*)src;
        float4 f1 = *(const float4*)(src + 4);
        float tmp[8] = {f0.x, f0.y, f0.z, f0.w, f1.x, f1.y, f1.z, f1.w};
        half8v hv, lv;
        #pragma unroll
        for (int e = 0; e < 8; ++e) {
            _Float16 hi = (_Float16)tmp[e];
            hv[e] = hi;
            lv[e] = (_Float16)(tmp[e] - (float)hi);
        }
        size_t dst = ((gbase + g) * 4 + hbase + hh) * (size_t)512 + lf * 8;
        *(half8v*)(oh + dst) = hv;
        *(half8v*)(ol + dst) = lv;
    }
}

// ---------------- Kernel 2: fused MFMA scores + ballot top-32 + final row write ----------------
// Block: 16 n-rows x 1024 u, 512 threads (8 waves). Wave w: u-strip [w*128, w*128+128) in the
// score phase (depth-1 B prefetch), rows {2w, 2w+1} in the select phase. b = blk&7 -> XCD affinity.
__global__ __launch_bounds__(512, 4) void scores_topk(
    const _Float16* __restrict__ qfh, const _Float16* __restrict__ qfl,
    const _Float16* __restrict__ kfh, const _Float16* __restrict__ kfl,
    const float* __restrict__ mlpw, const float* __restrict__ mlpb,
    float* __restrict__ adj)
{
    __shared__ float sc[16 * SROW];            // 64.25 KB scores
    __shared__ unsigned long long cand[8][64]; // 4 KB candidate buffers

    const int t = threadIdx.x;
    const int blk = blockIdx.x;
    const int b = blk & 7;                     // batch == XCD affinity (k stays L2-hot)
    const int gq = blk >> 3;                   // q row-group (16 rows)

    const int w = t >> 6, l = t & 63;
    const int quad = l >> 4, lane16 = l & 15;

    // A fragments: coalesced 16B loads from fragment-layout q
    half8v Ah[4], Al[4];
    #pragma unroll
    for (int h = 0; h < 4; ++h) {
        size_t a = (((size_t)b * QGROUPS + gq) * 4 + h) * 512 + l * 8;
        Ah[h] = *(const half8v*)(qfh + a);
        Al[h] = *(const half8v*)(qfl + a);
    }

    float2v mw2[4][4], mb2[4];
    #pragma unroll
    for (int o = 0; o < 4; ++o) {
        float bvo = mlpb[o];
        mb2[o] = (float2v){bvo, bvo};
        #pragma unroll
        for (int h = 0; h < 4; ++h) {
            float mwo = mlpw[o * 4 + h];
            mw2[o][h] = (float2v){mwo, mwo};
        }
    }
    const float2v z2 = {0.f, 0.f};

    // ---- score phase with depth-1 software pipeline on B fragments ----
    half8v Bh[4], Bl[4];
    {
        size_t a0 = (((size_t)b * KGROUPS + w * 8) * 4) * (size_t)512 + l * 8;
        #pragma unroll
        for (int h = 0; h < 4; ++h) {
            Bh[h] = *(const half8v*)(kfh + a0 + h * 512);
            Bl[h] = *(const half8v*)(kfl + a0 + h * 512);
        }
    }

    #pragma unroll
    for (int i = 0; i < 8; ++i) {
        const int g = w * 8 + i;               // u-group
        half8v Bhn[4], Bln[4];
        if (i < 7) {                           // prefetch next u-group while MFMAs run
            size_t a1 = (((size_t)b * KGROUPS + g + 1) * 4) * (size_t)512 + l * 8;
            #pragma unroll
            for (int h = 0; h < 4; ++h) {
                Bhn[h] = *(const half8v*)(kfh + a1 + h * 512);
                Bln[h] = *(const half8v*)(kfl + a1 + h * 512);
            }
        }

        float4v C[4];
        #pragma unroll
        for (int h = 0; h < 4; ++h) {
            float4v c = {0.f, 0.f, 0.f, 0.f};
            c = __builtin_amdgcn_mfma_f32_16x16x32_f16(Ah[h], Bh[h], c, 0, 0, 0);
            c = __builtin_amdgcn_mfma_f32_16x16x32_f16(Ah[h], Bl[h], c, 0, 0, 0);
            c = __builtin_amdgcn_mfma_f32_16x16x32_f16(Al[h], Bh[h], c, 0, 0, 0);
            C[h] = c;
        }

        // packed epilogue: rows in pairs (v_pk_fma_f32 / v_pk_add_f32 / v_pk_max_f32)
        #pragma unroll
        for (int r2 = 0; r2 < 2; ++r2) {
            float2v a0 = {C[0][2 * r2], C[0][2 * r2 + 1]};
            float2v a1 = {C[1][2 * r2], C[1][2 * r2 + 1]};
            float2v a2 = {C[2][2 * r2], C[2][2 * r2 + 1]};
            float2v a3 = {C[3][2 * r2], C[3][2 * r2 + 1]};
            float2v ssum = ((a0 + a1) + a2) + a3;
            #pragma unroll
            for (int o = 0; o < 4; ++o) {
                float2v to = a0 * mw2[o][0] + a1 * mw2[o][1] +
                             a2 * mw2[o][2] + a3 * mw2[o][3] + mb2[o];
                ssum += __builtin_elementwise_max(to, z2);
            }
            const int col = g * 16 + lane16;
            sc[(quad * 4 + 2 * r2) * SROW + col] = ssum[0];
            sc[(quad * 4 + 2 * r2 + 1) * SROW + col] = ssum[1];
        }

        if (i < 7) {
            #pragma unroll
            for (int h = 0; h < 4; ++h) { Bh[h] = Bhn[h]; Bl[h] = Bln[h]; }
        }
    }
    __syncthreads();

    // ---- top-32 per row; wave w handles rows 2w, 2w+1; ranking via ballot (no DS traffic) ----
    for (int rr = 0; rr < 2; ++rr) {
        const int row = w * 2 + rr;
        float* R = sc + row * SROW;

        float4 vv[4];   // lane l holds u-indices jj*256 + l*4 + e
        #pragma unroll
        for (int jj = 0; jj < 4; ++jj) vv[jj] = *(const float4*)(R + jj * 256 + l * 4);

        float m = vv[0].x;
        #pragma unroll
        for (int jj = 0; jj < 4; ++jj) {
            m = fmaxf(m, vv[jj].x); m = fmaxf(m, vv[jj].y);
            m = fmaxf(m, vv[jj].z); m = fmaxf(m, vv[jj].w);
        }

        // T = 32nd-largest lane-max, exact, via bitwise ballot search (order-preserving uint)
        unsigned km;
        { unsigned s = __float_as_uint(m); km = (s & 0x80000000u) ? ~s : (s | 0x80000000u); }
        unsigned accT = 0u;
        #pragma unroll
        for (int bit = 31; bit >= 0; --bit) {
            unsigned trial = accT | (1u << bit);
            if (__popcll(__ballot(km >= trial)) >= 32) accT = trial;
        }
        const float T = key_val(accT);   // >= 32 row elements are >= T, T <= true 32nd value

        // ballot-compact candidates >= T into cand[w][]
        cand[w][l] = 0ull;
        __builtin_amdgcn_wave_barrier();
        int total = 0;
        #pragma unroll
        for (int jj = 0; jj < 4; ++jj) {
            #pragma unroll
            for (int e = 0; e < 4; ++e) {
                float v = (e == 0) ? vv[jj].x : (e == 1) ? vv[jj].y : (e == 2) ? vv[jj].z : vv[jj].w;
                bool p = (v >= T);
                unsigned long long msk = __ballot(p);
                if (p) {
                    int pos = total + __popcll(msk & ((1ull << l) - 1ull));
                    if (pos < 64) cand[w][pos] = make_key(v, jj * 256 + l * 4 + e);
                }
                total += (int)__popcll(msk);
            }
        }
        __builtin_amdgcn_wave_barrier();

        bool win = false; float wval = 0.f; int widx = 0;
        if (total <= 64) {
            unsigned long long key = cand[w][l];   // one key per lane (0 = empty, sorts last)
            unsigned hi = (unsigned)(key >> 32), lo = (unsigned)key;

            unsigned X = 0u;
            #pragma unroll
            for (int bit = 31; bit >= 0; --bit) {
                unsigned trial = X | (1u << bit);
                if (__popcll(__ballot(hi >= trial)) >= 32) X = trial;
            }
            int cgt = __popcll(__ballot(hi > X));
            int rem = 32 - cgt;
            unsigned Y = 0u;
            #pragma unroll
            for (int bit = 9; bit >= 0; --bit) {
                unsigned trial = Y | (1u << bit);
                if (__popcll(__ballot(hi == X && lo >= trial)) >= rem) Y = trial;
            }
            if (hi > X || (hi == X && lo >= Y)) {   // exactly 32 winners
                win = true;
                wval = key_val(hi);
                widx = 1023 - (int)lo;
            }
        } else {
            // rare fallback: exact 32-round butterfly extraction
            float vals[16];
            #pragma unroll
            for (int jj = 0; jj < 4; ++jj) {
                vals[jj * 4 + 0] = vv[jj].x; vals[jj * 4 + 1] = vv[jj].y;
                vals[jj * 4 + 2] = vv[jj].z; vals[jj * 4 + 3] = vv[jj].w;
            }
            float selv = 0.f; int seli = 0;
            #pragma unroll 1
            for (int it = 0; it < 32; ++it) {
                float bv = -3.4e38f; int bi = 0x7fffffff;
                #pragma unroll
                for (int s = 0; s < 16; ++s) {
                    int idx2 = (s >> 2) * 256 + l * 4 + (s & 3);
                    if (vals[s] > bv) { bv = vals[s]; bi = idx2; }
                }
                #pragma unroll
                for (int off = 1; off < 64; off <<= 1) {
                    float ov = __shfl_xor(bv, off, 64);
                    int oi = __shfl_xor(bi, off, 64);
                    if (ov > bv || (ov == bv && oi < bi)) { bv = ov; bi = oi; }
                }
                if (l == it) { selv = bv; seli = bi; }
                if (((bi >> 2) & 63) == l) {
                    int slot = ((bi >> 8) << 2) + (bi & 3);
                    #pragma unroll
                    for (int s = 0; s < 16; ++s) if (s == slot) vals[s] = -3.4e38f;
                }
            }
            if (l < 32) { win = true; wval = selv; widx = seli; }
        }

        // rebuild the row in place (DS pipe is in-order per wave): b128 zeros, scatter winner
        __builtin_amdgcn_wave_barrier();
        #pragma unroll
        for (int jj = 0; jj < 4; ++jj)
            *(float4*)(R + jj * 256 + l * 4) = make_float4(0.f, 0.f, 0.f, 0.f);
        __builtin_amdgcn_wave_barrier();
        if (win) R[widx] = wval;
        __builtin_amdgcn_wave_barrier();

        // final coalesced write of the 2048-wide row (upper half zeros)
        float* rowptr = adj + ((size_t)(b * NODES + gq * 16 + row)) * NODES;
        #pragma unroll
        for (int jj = 0; jj < 8; ++jj) {
            int c4 = jj * 64 + l;
            float4 val;
            if (c4 < 256) val = *(const float4*)(R + c4 * 4);
            else          val = make_float4(0.f, 0.f, 0.f, 0.f);
            *(float4*)(rowptr + c4 * 4) = val;
        }
    }
}

extern "C" void kernel_launch(void* const* d_in, const int* in_sizes, int n_in,
                              void* d_out, int out_size, void* d_ws, size_t ws_size,
                              hipStream_t stream) {
    const float* x    = (const float*)d_in[0];
    const float* Wq   = (const float*)d_in[1];
    const float* bq   = (const float*)d_in[2];
    const float* Wk   = (const float*)d_in[3];
    const float* bk   = (const float*)d_in[4];
    const float* mlpw = (const float*)d_in[5];
    const float* mlpb = (const float*)d_in[6];
    // ln_g, ln_b feed only the deleted adj_static -> unused.

    _Float16* qfh = (_Float16*)d_ws;                        // 4 MB
    _Float16* qfl = qfh + (size_t)BATCH * NODES * DTOT;     // 4 MB
    _Float16* kfh = qfl + (size_t)BATCH * NODES * DTOT;     // 2 MB
    _Float16* kfl = kfh + (size_t)BATCH * NKEY * DTOT;      // 2 MB (total 12 MB)
    float* adj = (float*)d_out;

    proj_qk<<<dim3(BATCH * 96), dim3(256), 0, stream>>>(x, Wq, bq, Wk, bk, qfh, qfl, kfh, kfl);
    scores_topk<<<dim3(BATCH * QGROUPS), dim3(512), 0, stream>>>(qfh, qfl, kfh, kfl, mlpw, mlpb, adj);
}